// Round 6
// baseline (103.134 us; speedup 1.0000x reference)
//
#include <hip/hip_runtime.h>

#define BATCH 8
#define CC 32
#define FF 4
#define HH 128
#define WW 128
#define STRIDE 130          // even -> aligned float2 rows; 130*4=520 B row pitch
#define RP 1024.0f          // REPARAM_H == REPARAM_W
#define PS 16896            // per-plane stride in ws (floats); 129*130=16770 used
#define DEW 240             // guarded D row: [0,48) zero guard, [48,176] data, [176,240) right guard
#define DEBASE 48

// ---- K1: per-plane integral image -> ws ----
__global__ __launch_bounds__(1024) void ii_kernel(const float* __restrict__ in,
                                                  float* __restrict__ ws)
{
    __shared__ float ii[(HH + 1) * STRIDE + 4];    // +4 pad for float4 dump tail
    __shared__ float partial[8 * 128];

    const int plane = blockIdx.x;
    const int tid = threadIdx.x;
    const float* inp = in + (size_t)plane * (HH * WW);

    for (int i4 = tid; i4 < (HH * WW) / 4; i4 += 1024) {
        const float4 v = ((const float4*)inp)[i4];
        const int idx = i4 << 2;
        const int x = idx >> 7;
        const int y = idx & (WW - 1);
        float* dst = &ii[(x + 1) * STRIDE + (y + 1)];
        dst[0] = v.x; dst[1] = v.y; dst[2] = v.z; dst[3] = v.w;
    }
    if (tid <= HH) { ii[tid] = 0.0f; ii[tid * STRIDE] = 0.0f; }
    __syncthreads();

    {   // row cumsum, 8-way segmented
        const int row = tid & 127, seg = tid >> 7;
        float* p = &ii[(row + 1) * STRIDE + 1 + seg * 16];
        float v[16]; float s = 0.0f;
        #pragma unroll
        for (int j = 0; j < 16; ++j) { s += p[j]; v[j] = s; }
        partial[seg * 128 + row] = s;
        __syncthreads();
        float off = 0.0f;
        for (int k = 0; k < seg; ++k) off += partial[k * 128 + row];
        #pragma unroll
        for (int j = 0; j < 16; ++j) p[j] = v[j] + off;
    }
    __syncthreads();
    {   // col cumsum, 8-way segmented
        const int col = tid & 127, seg = tid >> 7;
        float* p = &ii[(seg * 16 + 1) * STRIDE + col + 1];
        float v[16]; float s = 0.0f;
        #pragma unroll
        for (int j = 0; j < 16; ++j) { s += p[j * STRIDE]; v[j] = s; }
        partial[seg * 128 + col] = s;
        __syncthreads();
        float off = 0.0f;
        for (int k = 0; k < seg; ++k) off += partial[k * 128 + col];
        #pragma unroll
        for (int j = 0; j < 16; ++j) p[j * STRIDE] = v[j] + off;
    }
    __syncthreads();

    // dump 129*130=16770 floats (4193 float4, 2 pad words) to ws
    float4* dst = (float4*)(ws + (size_t)plane * PS);
    for (int i = tid; i < 4193; i += 1024)
        dst[i] = *(const float4*)&ii[4 * i];
}

// ---- K2: barrier-free guarded stencil; rows from L2, De in per-wave LDS ----
__global__ __launch_bounds__(256) void box_kernel(
    const float* __restrict__ ws,
    const float* __restrict__ xmin_p,
    const float* __restrict__ xmax_p,
    const float* __restrict__ ymin_p,
    const float* __restrict__ ymax_p,
    float* __restrict__ out)
{
    __shared__ float de[4 * DEW];                  // 3840 B

    const int bid = blockIdx.x;
    const int plane = bid & 255;                   // plane-major: same XCD as K1's writer
    const int rest = bid >> 8;                     // 0..7
    const int f = rest & 3;
    const int hh = rest >> 2;
    const int c = plane & (CC - 1);
    const int tid = threadIdx.x;
    const int wave = tid >> 6;
    const int lane = tid & 63;
    const float* iip = ws + (size_t)plane * PS;

    float* De = &de[wave * DEW];
    if (lane < DEBASE) De[lane] = 0.0f;            // left guard (own slice, no barrier)

    const int pidx = c * FF + f;
    const float xmn = xmin_p[pidx] * RP;
    const float xmx = xmax_p[pidx] * RP;
    const float ymn = ymin_p[pidx] * RP;
    const float ymx = ymax_p[pidx] * RP;
    const float inv_area = 1.0f / ((xmx - xmn + 1.0f) * (ymx - ymn + 1.0f));
    const float ktf = floorf(xmn);          const int kt = (int)ktf;  const float ft = xmn - ktf;
    const float kbf = floorf(xmx + 1.0f);   const int kb = (int)kbf;  const float fb = xmx + 1.0f - kbf;
    const float klf = floorf(ymn);          const int kl = (int)klf;  const float fl = ymn - klf;
    const float krf = floorf(ymx + 1.0f);   const int kr = (int)krf;  const float fr = ymx + 1.0f - krf;
    const float gt = 1.0f - ft, gb = 1.0f - fb, gl = 1.0f - fl, gr = 1.0f - fr;
    const int al = kl & ~1, dl = kl - al;          // even base + uniform select
    const int ar = kr & ~1, dr = kr - ar;
    const float* Lp = &De[DEBASE + al + 2 * lane]; // min word 48-44 = 4
    const float* Rp = &De[DEBASE + ar + 2 * lane]; // max word 48+42+126+3 = 219 < 240
    float* outf = out + ((size_t)plane * FF + f) * (HH * WW);

    // virtual extension: row(x<0)==0 (ws row 0 is zeros), row(x>128)==row(128)
    const int h0 = hh * 64 + wave * 16;
    const int xt = h0 + kt;
    const int xb = h0 + kb;
    const float* p0 = &iip[min(max(xt, 0), 128) * STRIDE];
    const float* q0 = &iip[min(max(xb, 0), 128) * STRIDE];
    float2 tp = *(const float2*)&p0[2 * lane];  float tp2 = p0[128];
    float2 bp = *(const float2*)&q0[2 * lane];  float bp2 = q0[128];

    #pragma unroll 4
    for (int j = 0; j < 16; ++j) {
        const float* p = &iip[min(max(xt + j + 1, 0), 128) * STRIDE];
        const float* q = &iip[min(max(xb + j + 1, 0), 128) * STRIDE];
        const float2 tc = *(const float2*)&p[2 * lane];  const float tc2 = p[128];
        const float2 bc = *(const float2*)&q[2 * lane];  const float bc2 = q[128];

        const float d0   = (gb * bp.x + fb * bc.x) - (gt * tp.x + ft * tc.x);
        const float d1   = (gb * bp.y + fb * bc.y) - (gt * tp.y + ft * tc.y);
        const float d128 = (gb * bp2  + fb * bc2 ) - (gt * tp2  + ft * tc2 );

        *(float2*)&De[DEBASE + 2 * lane] = make_float2(d0, d1);
        De[DEBASE + 128 + lane] = d128;            // D[128] + right guard (y>=128 -> D[128])

        const float2 vL0 = *(const float2*)(Lp);
        const float2 vL1 = *(const float2*)(Lp + 2);
        const float2 vR0 = *(const float2*)(Rp);
        const float2 vR1 = *(const float2*)(Rp + 2);
        const float La = dl ? vL0.y : vL0.x;
        const float Lb = dl ? vL1.x : vL0.y;
        const float Lc = dl ? vL1.y : vL1.x;
        const float Ra = dr ? vR0.y : vR0.x;
        const float Rb = dr ? vR1.x : vR0.y;
        const float Rc = dr ? vR1.y : vR1.x;

        const float o0 = (gr * Ra + fr * Rb - gl * La - fl * Lb) * inv_area;
        const float o1 = (gr * Rb + fr * Rc - gl * Lb - fl * Lc) * inv_area;
        *(float2*)&outf[(h0 + j) * WW + 2 * lane] = make_float2(o0, o1);

        tp = tc; tp2 = tc2; bp = bc; bp2 = bc2;
    }
}

extern "C" void kernel_launch(void* const* d_in, const int* in_sizes, int n_in,
                              void* d_out, int out_size, void* d_ws, size_t ws_size,
                              hipStream_t stream) {
    const float* inp    = (const float*)d_in[0];
    const float* x_min  = (const float*)d_in[1];
    const float* x_max  = (const float*)d_in[2];
    const float* y_min  = (const float*)d_in[3];
    const float* y_max  = (const float*)d_in[4];
    float* out = (float*)d_out;
    float* ws  = (float*)d_ws;                     // 256 * 16896 * 4 B = 17.3 MB

    ii_kernel<<<dim3(BATCH * CC), dim3(1024), 0, stream>>>(inp, ws);
    box_kernel<<<dim3(8 * BATCH * CC), dim3(256), 0, stream>>>(ws, x_min, x_max, y_min, y_max, out);
}

// Round 7
// 99.712 us; speedup vs baseline: 1.0343x; 1.0343x over previous
//
#include <hip/hip_runtime.h>

#define BATCH 8
#define CC 32
#define FF 4
#define HH 128
#define WW 128
#define STRIDE 130          // even -> aligned float2 (b64) row reads in compute
#define RP 1024.0f          // REPARAM_H == REPARAM_W
#define NTHREADS 1024
#define NWAVES 16
#define CH 8                // h-rows per wave (128/16)
#define DEW 240             // guarded D row: [0,48) zero guard, [48,176] data, [176,240) right guard
#define DEBASE 48

__global__ __launch_bounds__(NTHREADS) void boxconv_kernel(
    const float* __restrict__ in,
    const float* __restrict__ xmin_p,
    const float* __restrict__ xmax_p,
    const float* __restrict__ ymin_p,
    const float* __restrict__ ymax_p,
    float* __restrict__ out)
{
    __shared__ float ii[(HH + 1) * STRIDE];        // 67080 B
    __shared__ float de[NWAVES * 2 * DEW];         // 30720 B (two De buffers per wave)
    __shared__ float partial[8 * 128];             // 4096 B  -> ~102 KB total, 1 block/CU

    const int plane = blockIdx.x;                  // b*CC + c
    const int c = plane & (CC - 1);
    const int tid = threadIdx.x;
    const int wave = tid >> 6;
    const int lane = tid & 63;
    const float* inp = in + (size_t)plane * (HH * WW);

    float* De0 = &de[(wave * 2 + 0) * DEW];
    float* De1 = &de[(wave * 2 + 1) * DEW];

    // ---- fused stage + row cumsum: thread (row r, seg s) scans its 16 floats in regs
    {
        const int r = tid >> 3, s = tid & 7;
        const float4* src = (const float4*)(inp + r * WW + s * 16);
        const float4 A = src[0], B = src[1], C4 = src[2], D4 = src[3];
        float t[16] = {A.x,A.y,A.z,A.w, B.x,B.y,B.z,B.w,
                       C4.x,C4.y,C4.z,C4.w, D4.x,D4.y,D4.z,D4.w};
        float v[16];
        float ssum = 0.0f;
        #pragma unroll
        for (int k = 0; k < 16; ++k) { ssum += t[k]; v[k] = ssum; }
        // exclusive prefix of segment sums within each 8-lane group (one row)
        float run = ssum;
        #pragma unroll
        for (int d = 1; d < 8; d <<= 1) {
            const float o = __shfl_up(run, (unsigned)d, 8);
            if ((lane & 7) >= d) run += o;
        }
        const float off = run - ssum;
        float* dst = &ii[(r + 1) * STRIDE + 1 + s * 16];
        #pragma unroll
        for (int k = 0; k < 16; ++k) dst[k] = v[k] + off;
    }
    if (tid <= HH) { ii[tid] = 0.0f; ii[tid * STRIDE] = 0.0f; }   // zero borders
    if (lane < DEBASE) { De0[lane] = 0.0f; De1[lane] = 0.0f; }    // left guards
    __syncthreads();

    // ---- col cumsum, 8-way segmented (seg uniform per wave)
    {
        const int col = tid & 127, seg = tid >> 7;
        float* p = &ii[(seg * 16 + 1) * STRIDE + col + 1];
        float v[16]; float sum = 0.0f;
        #pragma unroll
        for (int j = 0; j < 16; ++j) { sum += p[j * STRIDE]; v[j] = sum; }
        partial[seg * 128 + col] = sum;
        __syncthreads();
        float off = 0.0f;
        for (int k = 0; k < seg; ++k) off += partial[k * 128 + col];
        #pragma unroll
        for (int j = 0; j < 16; ++j) p[j * STRIDE] = v[j] + off;
    }
    __syncthreads();                               // last barrier — compute is barrier-free

    // ---- compute: dual-filter j-loop (2 independent chains), 2 px/lane, b64 LDS ops
    const int h0 = wave * CH;
    for (int fp = 0; fp < 2; ++fp) {
        // per-filter parameters
        int   kt[2], kb[2], dl[2], dr[2], xt[2], xb[2];
        float ft_[2], fb_[2], gt_[2], gb_[2], fl_[2], fr_[2], gl_[2], gr_[2], ia_[2];
        const float* Lp[2]; const float* Rp[2];
        float* Deb[2] = {De0, De1};
        float* outf[2];
        #pragma unroll
        for (int u = 0; u < 2; ++u) {
            const int f = fp * 2 + u;
            const int pidx = c * FF + f;
            const float xmn = xmin_p[pidx] * RP;
            const float xmx = xmax_p[pidx] * RP;
            const float ymn = ymin_p[pidx] * RP;
            const float ymx = ymax_p[pidx] * RP;
            ia_[u] = 1.0f / ((xmx - xmn + 1.0f) * (ymx - ymn + 1.0f));
            const float ktf = floorf(xmn);        kt[u] = (int)ktf;  ft_[u] = xmn - ktf;
            const float kbf = floorf(xmx + 1.0f); kb[u] = (int)kbf;  fb_[u] = xmx + 1.0f - kbf;
            const float klf = floorf(ymn);        const int kl = (int)klf;  fl_[u] = ymn - klf;
            const float krf = floorf(ymx + 1.0f); const int kr = (int)krf;  fr_[u] = ymx + 1.0f - krf;
            gt_[u] = 1.0f - ft_[u]; gb_[u] = 1.0f - fb_[u];
            gl_[u] = 1.0f - fl_[u]; gr_[u] = 1.0f - fr_[u];
            const int al = kl & ~1; dl[u] = kl - al;
            const int ar = kr & ~1; dr[u] = kr - ar;
            Lp[u] = &Deb[u][DEBASE + al + 2 * lane];
            Rp[u] = &Deb[u][DEBASE + ar + 2 * lane];
            outf[u] = out + ((size_t)plane * FF + f) * (HH * WW);
            xt[u] = h0 + kt[u];
            xb[u] = h0 + kb[u];
        }
        // prologue: first row pair per filter (virtual ext: x<0 -> row0 (zeros), x>128 -> row128)
        float2 tp[2], bp[2]; float tp2[2], bp2[2];
        #pragma unroll
        for (int u = 0; u < 2; ++u) {
            const float* p0 = &ii[min(max(xt[u], 0), 128) * STRIDE];
            const float* q0 = &ii[min(max(xb[u], 0), 128) * STRIDE];
            tp[u] = *(const float2*)&p0[2 * lane];  tp2[u] = p0[128];
            bp[u] = *(const float2*)&q0[2 * lane];  bp2[u] = q0[128];
        }

        #pragma unroll 4
        for (int j = 0; j < CH; ++j) {
            #pragma unroll
            for (int u = 0; u < 2; ++u) {
                const float* p = &ii[min(max(xt[u] + j + 1, 0), 128) * STRIDE];
                const float* q = &ii[min(max(xb[u] + j + 1, 0), 128) * STRIDE];
                const float2 tc = *(const float2*)&p[2 * lane];  const float tc2 = p[128];
                const float2 bc = *(const float2*)&q[2 * lane];  const float bc2 = q[128];

                const float d0   = (gb_[u] * bp[u].x + fb_[u] * bc.x) - (gt_[u] * tp[u].x + ft_[u] * tc.x);
                const float d1   = (gb_[u] * bp[u].y + fb_[u] * bc.y) - (gt_[u] * tp[u].y + ft_[u] * tc.y);
                const float d128 = (gb_[u] * bp2[u]  + fb_[u] * bc2 ) - (gt_[u] * tp2[u]  + ft_[u] * tc2 );

                *(float2*)&Deb[u][DEBASE + 2 * lane] = make_float2(d0, d1);
                Deb[u][DEBASE + 128 + lane] = d128;     // D[128] + right guard

                const float2 vL0 = *(const float2*)(Lp[u]);
                const float2 vL1 = *(const float2*)(Lp[u] + 2);
                const float2 vR0 = *(const float2*)(Rp[u]);
                const float2 vR1 = *(const float2*)(Rp[u] + 2);
                const float La = dl[u] ? vL0.y : vL0.x;
                const float Lb = dl[u] ? vL1.x : vL0.y;
                const float Lc = dl[u] ? vL1.y : vL1.x;
                const float Ra = dr[u] ? vR0.y : vR0.x;
                const float Rb = dr[u] ? vR1.x : vR0.y;
                const float Rc = dr[u] ? vR1.y : vR1.x;

                const float o0 = (gr_[u] * Ra + fr_[u] * Rb - gl_[u] * La - fl_[u] * Lb) * ia_[u];
                const float o1 = (gr_[u] * Rb + fr_[u] * Rc - gl_[u] * Lb - fl_[u] * Lc) * ia_[u];
                *(float2*)&outf[u][(h0 + j) * WW + 2 * lane] = make_float2(o0, o1);

                tp[u] = tc; tp2[u] = tc2; bp[u] = bc; bp2[u] = bc2;
            }
        }
    }
}

extern "C" void kernel_launch(void* const* d_in, const int* in_sizes, int n_in,
                              void* d_out, int out_size, void* d_ws, size_t ws_size,
                              hipStream_t stream) {
    const float* inp    = (const float*)d_in[0];
    const float* x_min  = (const float*)d_in[1];
    const float* x_max  = (const float*)d_in[2];
    const float* y_min  = (const float*)d_in[3];
    const float* y_max  = (const float*)d_in[4];
    float* out = (float*)d_out;

    dim3 grid(BATCH * CC);      // one block per (b,c) plane, 1 per CU
    dim3 block(NTHREADS);       // 16 waves
    boxconv_kernel<<<grid, block, 0, stream>>>(inp, x_min, x_max, y_min, y_max, out);
}